// Round 5
// baseline (232.689 us; speedup 1.0000x reference)
//
#include <hip/hip_runtime.h>

#define M_DIM 512
#define N_DIM 4096
#define K_DIM 4096

typedef __attribute__((ext_vector_type(4))) float f32x4;

// ---- ws layout (bytes) ----
// [0,1024)      float part_x[256]
// [1024,5120)   float part_w[1024]
// [5120,5128)   float amax_final[2]
// [8192, +2MB)  xq fp8
// [then, +16MB) wq fp8
#define PART_X_OFF 0
#define PART_X_N   256
#define PART_W_OFF 256
#define PART_W_N   1024
#define AMAX_OFF   1280
#define XQ_BYTE_OFF 8192
#define WQ_BYTE_OFF (XQ_BYTE_OFF + M_DIM * K_DIM)

// ---------------------------------------------------------------- amax ------
__global__ __launch_bounds__(256) void amax_kernel(
    const float4* __restrict__ x4, const float4* __restrict__ w4,
    float* __restrict__ ws_f) {
    const int b = blockIdx.x;
    float m = 0.0f;
    if (b < PART_X_N) {  // x: 256 blocks
        const int n4 = M_DIM * K_DIM / 4, stride = PART_X_N * 256;
        for (int i = b * 256 + threadIdx.x; i < n4; i += stride) {
            float4 a = x4[i];
            m = fmaxf(m, fmaxf(fmaxf(fabsf(a.x), fabsf(a.y)),
                               fmaxf(fabsf(a.z), fabsf(a.w))));
        }
    } else {             // w: 1024 blocks
        const int n4 = N_DIM * K_DIM / 4, stride = PART_W_N * 256;
        for (int i = (b - PART_X_N) * 256 + threadIdx.x; i < n4; i += stride) {
            float4 a = w4[i];
            m = fmaxf(m, fmaxf(fmaxf(fabsf(a.x), fabsf(a.y)),
                               fmaxf(fabsf(a.z), fabsf(a.w))));
        }
    }
    for (int off = 32; off > 0; off >>= 1)
        m = fmaxf(m, __shfl_down(m, off, 64));
    __shared__ float sm[4];
    if ((threadIdx.x & 63) == 0) sm[threadIdx.x >> 6] = m;
    __syncthreads();
    if (threadIdx.x == 0) {
        m = fmaxf(fmaxf(sm[0], sm[1]), fmaxf(sm[2], sm[3]));
        ws_f[(b < PART_X_N) ? (PART_X_OFF + b) : (PART_W_OFF + b - PART_X_N)] = m;
    }
}

// ------------------------------------------------------------- quantize -----
// e2m1 codebook values as OCP e4m3fn bytes (exact): 0,0.5,1,1.5,2,3,4,6.
// Midpoint ties -> smaller magnitude (matches jnp.argmin first-occurrence).
__device__ __forceinline__ unsigned int q1(float x, float s) {
    float a = fabsf(x) * s;
    unsigned int b;
    if      (a <= 0.25f) b = 0x00u;  // 0.0
    else if (a <= 0.75f) b = 0x30u;  // 0.5
    else if (a <= 1.25f) b = 0x38u;  // 1.0
    else if (a <= 1.75f) b = 0x3Cu;  // 1.5
    else if (a <= 2.5f)  b = 0x40u;  // 2.0
    else if (a <= 3.5f)  b = 0x44u;  // 3.0
    else if (a <= 5.0f)  b = 0x48u;  // 4.0
    else                 b = 0x4Cu;  // 6.0 (also handles clip)
    return b | ((__float_as_uint(x) >> 24) & 0x80u);
}
__device__ __forceinline__ unsigned int qpack4(float4 v, float s) {
    return q1(v.x, s) | (q1(v.y, s) << 8) | (q1(v.z, s) << 16) | (q1(v.w, s) << 24);
}

__global__ __launch_bounds__(256) void quant_kernel(
    const float4* __restrict__ x4, const float4* __restrict__ w4,
    float* __restrict__ ws_f, unsigned char* __restrict__ ws_b) {
    const int b = blockIdx.x, t = threadIdx.x;
    const bool is_x = b < 512;
    float m = 0.0f;
    if (is_x) {
        m = ws_f[PART_X_OFF + t];
    } else {
        for (int i = t; i < PART_W_N; i += 256)
            m = fmaxf(m, ws_f[PART_W_OFF + i]);
    }
    for (int off = 32; off > 0; off >>= 1)
        m = fmaxf(m, __shfl_down(m, off, 64));
    __shared__ float sm[4];
    if ((t & 63) == 0) sm[t >> 6] = m;
    __syncthreads();
    m = fmaxf(fmaxf(sm[0], sm[1]), fmaxf(sm[2], sm[3]));
    float amax = fmaxf(m, 1e-12f);
    float s = 6.0f / amax;
    if (t == 0 && b == 0)   ws_f[AMAX_OFF + 0] = amax;
    if (t == 0 && b == 512) ws_f[AMAX_OFF + 1] = amax;

    const float4* src = is_x ? x4 : w4;
    unsigned char* dstb = ws_b + (is_x ? XQ_BYTE_OFF : WQ_BYTE_OFF);
    const int idx16 = (is_x ? b : b - 512) * 256 + t;
    const float4* p = src + (size_t)idx16 * 4;
    uint4 o;
    o.x = qpack4(p[0], s);
    o.y = qpack4(p[1], s);
    o.z = qpack4(p[2], s);
    o.w = qpack4(p[3], s);
    ((uint4*)dstb)[idx16] = o;
}

// ----------------------------------------------------------------- GEMM -----
// C[m,n] = sum_k A[m,k]*B[n,k], fp8 operands (codebook units), FULL K per
// block. NO LDS, NO barriers: fragments load directly from global (operands
// are L2/LLC-resident: xq 2MB + per-XCD wq slice 2MB = one 4MB L2).
// 64x64 tile -> 512 blocks (2/CU); 4 waves in 2x2, each 32x32 via 2x2 of
// 16x16x32 fp8. Inner loop: 4 x 8B loads (immediate offsets) + 4 MFMA,
// zero VALU; latency hidden by ILP across the 16x-unrolled body.
__global__ __launch_bounds__(256, 2) void gemm_kernel(
    const unsigned char* __restrict__ A, const unsigned char* __restrict__ B,
    float* __restrict__ C, const float* __restrict__ amax2) {
    const int bid  = blockIdx.x;
    // bid = mt*64 + g*8 + x : x = XCD slice (N), g = n-subtile, mt = m-tile
    const int bm   = (bid >> 6) * 64;
    const int bn   = ((bid & 7) * 8 + ((bid >> 3) & 7)) * 64;
    const int lane = threadIdx.x & 63;
    const int wave = threadIdx.x >> 6;
    const int wm   = (wave >> 1) * 32;
    const int wn   = (wave & 1) * 32;
    const int t15  = lane & 15;
    const int quad = lane >> 4;

    const float cs = (1.0f / (6.0f / fmaxf(amax2[0], 1e-12f))) *
                     (1.0f / (6.0f / fmaxf(amax2[1], 1e-12f)));

    // fragment base pointers: row*K + quad*8 (A-frag lane layout for
    // 16x16x32 fp8: lane = 16*quad + m, holds k = quad*8..+8 of each 32-blk)
    const unsigned char* ap0 = A + (size_t)(bm + wm + t15) * K_DIM + quad * 8;
    const unsigned char* ap1 = ap0 + 16 * K_DIM;
    const unsigned char* bp0 = B + (size_t)(bn + wn + t15) * K_DIM + quad * 8;
    const unsigned char* bp1 = bp0 + 16 * K_DIM;

    f32x4 acc[2][2] = {};

    for (int ko = 0; ko < K_DIM / 512; ko++) {   // 8 outer iters
#pragma unroll
        for (int u = 0; u < 16; u++) {           // imm offsets 0..480 (+8)
            const long a0v = *(const long*)(ap0 + u * 32);
            const long a1v = *(const long*)(ap1 + u * 32);
            const long b0v = *(const long*)(bp0 + u * 32);
            const long b1v = *(const long*)(bp1 + u * 32);
            acc[0][0] = __builtin_amdgcn_mfma_f32_16x16x32_fp8_fp8(
                a0v, b0v, acc[0][0], 0, 0, 0);
            acc[0][1] = __builtin_amdgcn_mfma_f32_16x16x32_fp8_fp8(
                a0v, b1v, acc[0][1], 0, 0, 0);
            acc[1][0] = __builtin_amdgcn_mfma_f32_16x16x32_fp8_fp8(
                a1v, b0v, acc[1][0], 0, 0, 0);
            acc[1][1] = __builtin_amdgcn_mfma_f32_16x16x32_fp8_fp8(
                a1v, b1v, acc[1][1], 0, 0, 0);
        }
        ap0 += 512; ap1 += 512; bp0 += 512; bp1 += 512;
    }

    // C/D layout: col = lane&15 (n), row = quad*4 + reg (m). Plain stores.
#pragma unroll
    for (int i = 0; i < 2; i++)
#pragma unroll
        for (int j = 0; j < 2; j++) {
            const int m0 = bm + wm + i * 16 + quad * 4;
            const int n0 = bn + wn + j * 16 + t15;
#pragma unroll
            for (int r = 0; r < 4; r++)
                C[(size_t)(m0 + r) * N_DIM + n0] = acc[i][j][r] * cs;
        }
}

// ---------------------------------------------------------------- launch ----
extern "C" void kernel_launch(void* const* d_in, const int* in_sizes, int n_in,
                              void* d_out, int out_size, void* d_ws, size_t ws_size,
                              hipStream_t stream) {
    const float* x = (const float*)d_in[0];   // [512, 4096]
    const float* w = (const float*)d_in[1];   // [4096, 4096]
    float* out = (float*)d_out;               // [512, 4096]

    float* ws_f = (float*)d_ws;
    unsigned char* ws_b = (unsigned char*)d_ws;
    const unsigned char* xq = ws_b + XQ_BYTE_OFF;
    const unsigned char* wq = ws_b + WQ_BYTE_OFF;

    amax_kernel<<<PART_X_N + PART_W_N, 256, 0, stream>>>(
        (const float4*)x, (const float4*)w, ws_f);
    quant_kernel<<<512 + 4096, 256, 0, stream>>>(
        (const float4*)x, (const float4*)w, ws_f, ws_b);
    gemm_kernel<<<(M_DIM / 64) * (N_DIM / 64), 256, 0, stream>>>(
        xq, wq, out, ws_f + AMAX_OFF);
}

// Round 6
// 135.847 us; speedup vs baseline: 1.7129x; 1.7129x over previous
//
#include <hip/hip_runtime.h>

#define M_DIM 512
#define N_DIM 4096
#define K_DIM 4096

typedef __attribute__((ext_vector_type(4))) float f32x4;

// ---- ws layout (bytes) ----
// [0,1024)      float part_x[256]
// [1024,5120)   float part_w[1024]
// [5120,5128)   float amax_final[2]
// [8192, +2MB)  xq fp8
// [then, +16MB) wq fp8
#define PART_X_OFF 0
#define PART_X_N   256
#define PART_W_OFF 256
#define PART_W_N   1024
#define AMAX_OFF   1280
#define XQ_BYTE_OFF 8192
#define WQ_BYTE_OFF (XQ_BYTE_OFF + M_DIM * K_DIM)

// ---------------------------------------------------------------- amax ------
__global__ __launch_bounds__(256) void amax_kernel(
    const float4* __restrict__ x4, const float4* __restrict__ w4,
    float* __restrict__ ws_f) {
    const int b = blockIdx.x;
    float m = 0.0f;
    if (b < PART_X_N) {  // x: 256 blocks
        const int n4 = M_DIM * K_DIM / 4, stride = PART_X_N * 256;
        for (int i = b * 256 + threadIdx.x; i < n4; i += stride) {
            float4 a = x4[i];
            m = fmaxf(m, fmaxf(fmaxf(fabsf(a.x), fabsf(a.y)),
                               fmaxf(fabsf(a.z), fabsf(a.w))));
        }
    } else {             // w: 1024 blocks
        const int n4 = N_DIM * K_DIM / 4, stride = PART_W_N * 256;
        for (int i = (b - PART_X_N) * 256 + threadIdx.x; i < n4; i += stride) {
            float4 a = w4[i];
            m = fmaxf(m, fmaxf(fmaxf(fabsf(a.x), fabsf(a.y)),
                               fmaxf(fabsf(a.z), fabsf(a.w))));
        }
    }
    for (int off = 32; off > 0; off >>= 1)
        m = fmaxf(m, __shfl_down(m, off, 64));
    __shared__ float sm[4];
    if ((threadIdx.x & 63) == 0) sm[threadIdx.x >> 6] = m;
    __syncthreads();
    if (threadIdx.x == 0) {
        m = fmaxf(fmaxf(sm[0], sm[1]), fmaxf(sm[2], sm[3]));
        ws_f[(b < PART_X_N) ? (PART_X_OFF + b) : (PART_W_OFF + b - PART_X_N)] = m;
    }
}

// ------------------------------------------------------------- quantize -----
// e2m1 codebook values as OCP e4m3fn bytes (exact): 0,0.5,1,1.5,2,3,4,6.
// Midpoint ties -> smaller magnitude (matches jnp.argmin first-occurrence).
__device__ __forceinline__ unsigned int q1(float x, float s) {
    float a = fabsf(x) * s;
    unsigned int b;
    if      (a <= 0.25f) b = 0x00u;  // 0.0
    else if (a <= 0.75f) b = 0x30u;  // 0.5
    else if (a <= 1.25f) b = 0x38u;  // 1.0
    else if (a <= 1.75f) b = 0x3Cu;  // 1.5
    else if (a <= 2.5f)  b = 0x40u;  // 2.0
    else if (a <= 3.5f)  b = 0x44u;  // 3.0
    else if (a <= 5.0f)  b = 0x48u;  // 4.0
    else                 b = 0x4Cu;  // 6.0 (also handles clip)
    return b | ((__float_as_uint(x) >> 24) & 0x80u);
}
__device__ __forceinline__ unsigned int qpack4(float4 v, float s) {
    return q1(v.x, s) | (q1(v.y, s) << 8) | (q1(v.z, s) << 16) | (q1(v.w, s) << 24);
}

__global__ __launch_bounds__(256) void quant_kernel(
    const float4* __restrict__ x4, const float4* __restrict__ w4,
    float* __restrict__ ws_f, unsigned char* __restrict__ ws_b) {
    const int b = blockIdx.x, t = threadIdx.x;
    const bool is_x = b < 512;
    float m = 0.0f;
    if (is_x) {
        m = ws_f[PART_X_OFF + t];
    } else {
        for (int i = t; i < PART_W_N; i += 256)
            m = fmaxf(m, ws_f[PART_W_OFF + i]);
    }
    for (int off = 32; off > 0; off >>= 1)
        m = fmaxf(m, __shfl_down(m, off, 64));
    __shared__ float sm[4];
    if ((t & 63) == 0) sm[t >> 6] = m;
    __syncthreads();
    m = fmaxf(fmaxf(sm[0], sm[1]), fmaxf(sm[2], sm[3]));
    float amax = fmaxf(m, 1e-12f);
    float s = 6.0f / amax;
    if (t == 0 && b == 0)   ws_f[AMAX_OFF + 0] = amax;
    if (t == 0 && b == 512) ws_f[AMAX_OFF + 1] = amax;

    const float4* src = is_x ? x4 : w4;
    unsigned char* dstb = ws_b + (is_x ? XQ_BYTE_OFF : WQ_BYTE_OFF);
    const int idx16 = (is_x ? b : b - 512) * 256 + t;
    const float4* p = src + (size_t)idx16 * 4;
    uint4 o;
    o.x = qpack4(p[0], s);
    o.y = qpack4(p[1], s);
    o.z = qpack4(p[2], s);
    o.w = qpack4(p[3], s);
    ((uint4*)dstb)[idx16] = o;
}

// ----------------------------------------------------------------- GEMM -----
__device__ __forceinline__ void async_copy16(const void* g, void* l) {
    __builtin_amdgcn_global_load_lds(
        (const __attribute__((address_space(1))) unsigned int*)g,
        (__attribute__((address_space(3))) unsigned int*)l, 16, 0, 0);
}

// C[m,n] = sum_k A[m,k]*B[n,k], fp8 operands (codebook units), FULL K per
// block, plain stores. 64x64 tile -> 512 blocks (2/CU); 4 waves 2x2, each
// 32x32 via 2x2 of 16x16x32 fp8. BK=512: only 8 barrier-drains per block
// (R4's BK=64 had 64 -> drain-latency-bound at 41.6us). LDS 64KB/block,
// 2 blocks/CU = 128KB <= 160KB. 16B-granule XOR swizzle (pcol ^ row&31)
// puts b64 frag reads at the wave64 bank floor.
__global__ __launch_bounds__(256, 2) void gemm_kernel(
    const unsigned char* __restrict__ A, const unsigned char* __restrict__ B,
    float* __restrict__ C, const float* __restrict__ amax2) {
    __shared__ __align__(16) unsigned char As[64 * 512];
    __shared__ __align__(16) unsigned char Bs[64 * 512];

    const int bid  = blockIdx.x;
    // bid = mt*64 + g*8 + x : x = XCD slice (N), g = n-subtile, mt = m-tile
    const int bm   = (bid >> 6) * 64;
    const int bn   = ((bid & 7) * 8 + ((bid >> 3) & 7)) * 64;
    const int tid  = threadIdx.x;
    const int lane = tid & 63;
    const int wave = tid >> 6;
    const int wm   = (wave >> 1) * 32;
    const int wn   = (wave & 1) * 32;
    const int t15  = lane & 15;
    const int quad = lane >> 4;

    const float cs = (1.0f / (6.0f / fmaxf(amax2[0], 1e-12f))) *
                     (1.0f / (6.0f / fmaxf(amax2[1], 1e-12f)));

    // staging: chunk c = j*256 + tid (j=0..7 each for A,B), LDS byte c*16
    // (wave-uniform base + lane*16 ✓). Physical slot (row=c>>5, pcol=c&31)
    // holds global 16B-chunk gk = pcol ^ (row&31) of that row.
    const unsigned char* agp[8];
    const unsigned char* bgp[8];
#pragma unroll
    for (int j = 0; j < 8; j++) {
        const int c = j * 256 + tid;
        const int row = c >> 5, pcol = c & 31;
        const int gk = pcol ^ (row & 31);
        agp[j] = A + (size_t)(bm + row) * K_DIM + gk * 16;
        bgp[j] = B + (size_t)(bn + row) * K_DIM + gk * 16;
    }

    f32x4 acc[2][2] = {};
    const int ra0 = wm + t15, ra1 = ra0 + 16;
    const int rb0 = wn + t15, rb1 = rb0 + 16;
    const int qh = quad >> 1, qb = (quad & 1) * 8;

    for (int ko = 0; ko < K_DIM; ko += 512) {
#pragma unroll
        for (int j = 0; j < 8; j++) {
            async_copy16(agp[j] + ko, As + (j * 256 + tid) * 16);
            async_copy16(bgp[j] + ko, Bs + (j * 256 + tid) * 16);
        }
        __syncthreads();

#pragma unroll
        for (int kb = 0; kb < 16; kb++) {
            const int g = 2 * kb + qh;  // global 16B chunk of this k-block
            const long a0 = *(const long*)(As + ra0 * 512 + ((g ^ (ra0 & 31)) * 16) + qb);
            const long a1 = *(const long*)(As + ra1 * 512 + ((g ^ (ra1 & 31)) * 16) + qb);
            const long b0 = *(const long*)(Bs + rb0 * 512 + ((g ^ (rb0 & 31)) * 16) + qb);
            const long b1 = *(const long*)(Bs + rb1 * 512 + ((g ^ (rb1 & 31)) * 16) + qb);
            acc[0][0] = __builtin_amdgcn_mfma_f32_16x16x32_fp8_fp8(a0, b0, acc[0][0], 0, 0, 0);
            acc[0][1] = __builtin_amdgcn_mfma_f32_16x16x32_fp8_fp8(a0, b1, acc[0][1], 0, 0, 0);
            acc[1][0] = __builtin_amdgcn_mfma_f32_16x16x32_fp8_fp8(a1, b0, acc[1][0], 0, 0, 0);
            acc[1][1] = __builtin_amdgcn_mfma_f32_16x16x32_fp8_fp8(a1, b1, acc[1][1], 0, 0, 0);
        }
        __syncthreads();
    }

    // C/D layout: col = lane&15 (n), row = quad*4 + reg (m). Plain stores.
#pragma unroll
    for (int i = 0; i < 2; i++)
#pragma unroll
        for (int j = 0; j < 2; j++) {
            const int m0 = bm + wm + i * 16 + quad * 4;
            const int n0 = bn + wn + j * 16 + t15;
#pragma unroll
            for (int r = 0; r < 4; r++)
                C[(size_t)(m0 + r) * N_DIM + n0] = acc[i][j][r] * cs;
        }
}

// ---------------------------------------------------------------- launch ----
extern "C" void kernel_launch(void* const* d_in, const int* in_sizes, int n_in,
                              void* d_out, int out_size, void* d_ws, size_t ws_size,
                              hipStream_t stream) {
    const float* x = (const float*)d_in[0];   // [512, 4096]
    const float* w = (const float*)d_in[1];   // [4096, 4096]
    float* out = (float*)d_out;               // [512, 4096]

    float* ws_f = (float*)d_ws;
    unsigned char* ws_b = (unsigned char*)d_ws;
    const unsigned char* xq = ws_b + XQ_BYTE_OFF;
    const unsigned char* wq = ws_b + WQ_BYTE_OFF;

    amax_kernel<<<PART_X_N + PART_W_N, 256, 0, stream>>>(
        (const float4*)x, (const float4*)w, ws_f);
    quant_kernel<<<512 + 4096, 256, 0, stream>>>(
        (const float4*)x, (const float4*)w, ws_f, ws_b);
    gemm_kernel<<<(M_DIM / 64) * (N_DIM / 64), 256, 0, stream>>>(
        xq, wq, out, ws_f + AMAX_OFF);
}